// Round 7
// baseline (3248.293 us; speedup 1.0000x reference)
//
#include <hip/hip_runtime.h>
#include <hip/hip_bf16.h>

typedef _Float16 f16;
typedef __attribute__((ext_vector_type(8))) _Float16 f16x8;
typedef __attribute__((ext_vector_type(4))) _Float16 f16x4;
typedef __attribute__((ext_vector_type(4))) float f32x4;

#define DEVI __device__ __forceinline__

DEVI float ldf(const void* p, size_t i, int isf32) {
    if (isf32) return ((const float*)p)[i];
    unsigned int u = ((const unsigned short*)p)[i];
    union { unsigned int b; float f; } c; c.b = u << 16;
    return c.f;
}

DEVI void gld_lds16(const f16* g, f16* l) {
    __builtin_amdgcn_global_load_lds(
        (__attribute__((address_space(1))) void*)(g),
        (__attribute__((address_space(3))) void*)(l), 16, 0, 0);
}

__global__ void detect_dtype(const void* qt, int* flag) {
    if (threadIdx.x == 0 && blockIdx.x == 0) {
        const unsigned int* w = (const unsigned int*)qt;
        int cnt = 0;
        for (int i = 0; i < 64; ++i) {
            unsigned int lo = w[i] & 0xFFFFu;
            union { unsigned int b; float f; } c; c.b = lo << 16;
            if (c.f >= 1e-4f && c.f <= 100.5f) ++cnt;
        }
        *flag = (cnt >= 32) ? 0 : 1;   // 0 = bf16, 1 = fp32
    }
}

__global__ __launch_bounds__(256)
void cvt_in(const void* __restrict__ src, float* __restrict__ dst, int n,
            const int* __restrict__ flag) {
    const int f32 = *flag;
    int i = blockIdx.x * 256 + threadIdx.x;
    if (i < n) dst[i] = ldf(src, i, f32);
}

__global__ __launch_bounds__(256)
void fill_out(float* out, float v) {
    out[blockIdx.x * 256 + threadIdx.x] = v;
}

// =====================================================================
// Software-pipelined MFMA GEMM. BK=32, double-buffered LDS, raw barriers
// + manual vmcnt(4): stage s+1's global_load_lds issued during stage s,
// so staging latency overlaps MFMA (AITER-style; __syncthreads would
// force a vmcnt(0) drain every iteration).
// 1D M-chunk-swizzled grid as before. MT M-tiles per block share one
// continuous pipeline (no drain at tile boundaries except epilogue vmem).
// EPI: 0 bias->f16 ; 1 bias+res->f16 ; 2 bias+gelu->f16 ; 3 bias->f32
// =====================================================================
template<int EPI>
__global__ __launch_bounds__(256, 4)
void gemm_bt(const f16* __restrict__ Ag, const f16* __restrict__ BTg,
             const float* __restrict__ biasg, const f16* __restrict__ resg,
             void* __restrict__ outg,
             int NT, int NTZ, int MCHUNK, int MT, int N, int K, int lda,
             long zsB, long zsBias, long zsC)
{
    const int tid  = threadIdx.x;
    const int w    = tid >> 6, lane = tid & 63;
    const int wm   = w >> 1,   wn   = w & 1;

    const int id    = blockIdx.x;
    const int pc    = MCHUNK * NTZ;
    const int chunk = id / pc;
    const int rem   = id - chunk * pc;
    const int mloc  = rem % MCHUNK;
    const int ynz   = rem / MCHUNK;
    const int z     = ynz / NT;
    const int tmB   = (chunk * MCHUNK + mloc) * (128 * MT);
    const int tn    = (ynz - z * NT) * 128;

    const f16*   BT   = BTg + (size_t)z * zsB;
    const float* bias = biasg + (size_t)z * zsBias;
    const size_t zoffC = (size_t)z * zsC;

    __shared__ __align__(16) f16 smA[2][8][64][8];   // 16 KB
    __shared__ __align__(16) f16 smB[2][8][64][8];   // 16 KB

    const int r16 = lane & 15, q4 = lane >> 4;
    const int iters = K >> 5;                        // BK = 32

    // wave w stages A sub-blocks {2w,2w+1} and B sub-blocks {2w,2w+1}
    const f16* gA0 = Ag + (size_t)(tmB + (2 * w)     * 16 + r16) * lda + q4 * 8;
    const f16* gA1 = gA0 + (size_t)16 * lda;
    const f16* gB0 = BT + (size_t)(tn  + (2 * w)     * 16 + r16) * K   + q4 * 8;
    const f16* gB1 = gB0 + (size_t)16 * K;

    auto issue = [&](int msN, int ktN, int buf) {
        const size_t aoff = (size_t)msN * 128 * lda + (size_t)ktN * 32;
        const size_t boff = (size_t)ktN * 32;
        gld_lds16(gA0 + aoff, &smA[buf][2 * w][0][0]);
        gld_lds16(gA1 + aoff, &smA[buf][2 * w + 1][0][0]);
        gld_lds16(gB0 + boff, &smB[buf][2 * w][0][0]);
        gld_lds16(gB1 + boff, &smB[buf][2 * w + 1][0][0]);
    };

    issue(0, 0, 0);                                  // prologue prefetch
    int stage = 0;

    for (int ms = 0; ms < MT; ++ms) {
        const int tm = tmB + ms * 128;

        f32x4 acc[4][4];
#pragma unroll
        for (int i = 0; i < 4; ++i)
#pragma unroll
            for (int j = 0; j < 4; ++j) acc[i][j] = (f32x4)0.0f;

        for (int kt = 0; kt < iters; ++kt, ++stage) {
            const int cur = stage & 1;
            __builtin_amdgcn_s_barrier();            // all waves done reading buf cur^1
            int ktN = kt + 1, msN = ms;
            if (ktN == iters) { ktN = 0; ++msN; }
            if (msN < MT) {
                issue(msN, ktN, cur ^ 1);            // prefetch next stage
                __builtin_amdgcn_s_waitcnt(0x0F74);  // vmcnt(4): cur loads done
            } else {
                __builtin_amdgcn_s_waitcnt(0x0F70);  // vmcnt(0)
            }
            __builtin_amdgcn_s_barrier();            // cur visible to all waves
            __asm__ __volatile__("" ::: "memory");   // pin LDS reads below

            f16x8 af[4], bf[4];
#pragma unroll
            for (int i = 0; i < 4; ++i) {
                af[i] = *(const f16x8*)&smA[cur][wm * 4 + i][lane][0];
                bf[i] = *(const f16x8*)&smB[cur][wn * 4 + i][lane][0];
            }
#pragma unroll
            for (int i = 0; i < 4; ++i)
#pragma unroll
                for (int j = 0; j < 4; ++j)
                    acc[i][j] = __builtin_amdgcn_mfma_f32_16x16x32_f16(
                        af[i], bf[j], acc[i][j], 0, 0, 0);
        }

        // epilogue for tile ms (next tile's k=0 prefetch already in flight)
        const int rowBase = tm + wm * 64;
        const int colBase = tn + wn * 64;
#pragma unroll
        for (int j = 0; j < 4; ++j) {
            const int col = colBase + j * 16 + r16;
            const float bv = bias[col];
#pragma unroll
            for (int i = 0; i < 4; ++i) {
                const int row0 = rowBase + i * 16 + q4 * 4;
#pragma unroll
                for (int r = 0; r < 4; ++r) {
                    const int row = row0 + r;
                    const size_t off = (size_t)row * N + col;
                    float v = acc[i][j][r] + bv;
                    if constexpr (EPI == 0) {
                        ((f16*)outg)[zoffC + off] = (f16)v;
                    } else if constexpr (EPI == 1) {
                        v += (float)resg[off];
                        ((f16*)outg)[off] = (f16)v;
                    } else if constexpr (EPI == 2) {
                        float t  = v + 0.044715f * v * v * v;
                        float u  = 1.5957691216057308f * t;   // 2*sqrt(2/pi)*t
                        float e  = __expf(u);
                        float th = 1.0f - 2.0f / (e + 1.0f); // tanh(u/2)
                        ((f16*)outg)[off] = (f16)(0.5f * v * (1.0f + th));
                    } else {
                        ((float*)outg)[off] = v;
                    }
                }
            }
        }
    }
}

// =====================================================================
// Attention: 1 wave per batch j in [0,16384); slab j*1024 viewed [8][128]
// (raw torch-.view semantics); bias row = j mod 4096.
// small=1: Q/K/V are deduped [1024][512] (layer 0), slab = b*4096 + h*1024.
// =====================================================================
__global__ __launch_bounds__(256)
void attn_kernel(const f16* __restrict__ qg, const f16* __restrict__ kg,
                 const f16* __restrict__ vg, const float* __restrict__ biasL,
                 f16* __restrict__ cg, int small)
{
    const int w = threadIdx.x >> 6, lane = threadIdx.x & 63;
    const int j = blockIdx.x * 4 + w;
    __shared__ __align__(16) f16 sQ[4][8][136];
    __shared__ __align__(16) f16 sK[4][8][136];
    __shared__ __align__(16) f16 sV[4][8][136];
    __shared__ float sP[4][8][8];

    const size_t base  = (size_t)j * 1024;
    const size_t ibase = small ? ((size_t)(j >> 7) * 4096 + (size_t)(j & 3) * 1024)
                               : base;
#pragma unroll
    for (int t = 0; t < 2; ++t) {
        int flat = (t * 64 + lane) * 8;
        int r = flat >> 7, c = flat & 127;
        *(f16x8*)&sQ[w][r][c] = *(const f16x8*)(qg + ibase + flat);
        *(f16x8*)&sK[w][r][c] = *(const f16x8*)(kg + ibase + flat);
        *(f16x8*)&sV[w][r][c] = *(const f16x8*)(vg + ibase + flat);
    }
    __syncthreads();

    const int i = lane >> 3, jj = lane & 7;
    float d = 0.f;
#pragma unroll
    for (int c = 0; c < 16; ++c) {
        f16x8 qv = *(const f16x8*)&sQ[w][i][c * 8];
        f16x8 kv = *(const f16x8*)&sK[w][jj][c * 8];
#pragma unroll
        for (int e = 0; e < 8; ++e) d += (float)qv[e] * (float)kv[e];
    }
    float s = d * 0.17677669529663687f + biasL[(size_t)(j & 4095) * 64 + lane];
    float mx = s;
    mx = fmaxf(mx, __shfl_xor(mx, 1, 64));
    mx = fmaxf(mx, __shfl_xor(mx, 2, 64));
    mx = fmaxf(mx, __shfl_xor(mx, 4, 64));
    float p = __expf(s - mx);
    float sum = p;
    sum += __shfl_xor(sum, 1, 64);
    sum += __shfl_xor(sum, 2, 64);
    sum += __shfl_xor(sum, 4, 64);
    sP[w][i][jj] = p / sum;
    __syncthreads();

#pragma unroll
    for (int t2 = 0; t2 < 8; ++t2) {
        float ap[8];
#pragma unroll
        for (int e = 0; e < 8; ++e) ap[e] = sP[w][t2][e];
#pragma unroll
        for (int h = 0; h < 2; ++h) {
            int flat = (t2 * 2 + h) * 64 + lane;
            int dd = flat & 127;
            float o = 0.f;
#pragma unroll
            for (int e = 0; e < 8; ++e) o += ap[e] * (float)sV[w][e][dd];
            cg[base + flat] = (f16)o;
        }
    }
}

// =====================================================================
// Row LayerNorm over 512 cols, f16 in -> f16 out (in-place safe). 1 wave/row.
// =====================================================================
__global__ __launch_bounds__(256)
void ln_kernel(const f16* __restrict__ X, const float* __restrict__ g,
               const float* __restrict__ b, f16* __restrict__ Y)
{
    const int w = threadIdx.x >> 6, lane = threadIdx.x & 63;
    const int row = blockIdx.x * 4 + w;
    f16x8 v = *(const f16x8*)(X + (size_t)row * 512 + lane * 8);
    float vf[8]; float s = 0.f, ss = 0.f;
#pragma unroll
    for (int e = 0; e < 8; ++e) { vf[e] = (float)v[e]; s += vf[e]; ss += vf[e] * vf[e]; }
#pragma unroll
    for (int m = 1; m <= 32; m <<= 1) {
        s  += __shfl_xor(s, m, 64);
        ss += __shfl_xor(ss, m, 64);
    }
    const float mu  = s * (1.0f / 512.0f);
    const float var = ss * (1.0f / 512.0f) - mu * mu;
    const float rs  = rsqrtf(var + 1e-5f);
    f32x4 g0 = *(const f32x4*)(g + lane * 8), g1 = *(const f32x4*)(g + lane * 8 + 4);
    f32x4 b0 = *(const f32x4*)(b + lane * 8), b1 = *(const f32x4*)(b + lane * 8 + 4);
    f16x8 y;
#pragma unroll
    for (int e = 0; e < 4; ++e) {
        y[e]     = (f16)(g0[e] * (vf[e]     - mu) * rs + b0[e]);
        y[e + 4] = (f16)(g1[e] * (vf[e + 4] - mu) * rs + b1[e]);
    }
    *(f16x8*)(Y + (size_t)row * 512 + lane * 8) = y;
}

// =====================================================================
// x0 builders
// =====================================================================
__global__ __launch_bounds__(256)
void build_x0(const void* __restrict__ sup, const void* __restrict__ cls,
              f16* __restrict__ xb, const int* __restrict__ flag)
{
    const int f32 = *flag;
    const size_t idx = ((size_t)blockIdx.x * 256 + threadIdx.x) * 4;
    const int row = (int)(idx >> 9), col0 = (int)(idx & 511);
    const int s = row & 7, b = row >> 8;
    f16x4 o;
#pragma unroll
    for (int e = 0; e < 4; ++e) {
        const int md = (col0 + e) & 127;
        float v = (s == 0) ? ldf(cls, md, f32)
                           : ldf(sup, ((size_t)b * 7 + (s - 1)) * 128 + md, f32);
        o[e] = (f16)v;
    }
    *(f16x4*)(xb + idx) = o;
}

// deduped x0: [b*8+s][512]
__global__ __launch_bounds__(256)
void build_x0s(const void* __restrict__ sup, const void* __restrict__ cls,
               f16* __restrict__ xs, const int* __restrict__ flag)
{
    const int f32 = *flag;
    const size_t idx = ((size_t)blockIdx.x * 256 + threadIdx.x) * 4;  // 524288 total
    const int row = (int)(idx >> 9), col0 = (int)(idx & 511);
    const int s = row & 7, b = row >> 3;
    f16x4 o;
#pragma unroll
    for (int e = 0; e < 4; ++e) {
        const int md = (col0 + e) & 127;
        float v = (s == 0) ? ldf(cls, md, f32)
                           : ldf(sup, ((size_t)b * 7 + (s - 1)) * 128 + md, f32);
        o[e] = (f16)v;
    }
    *(f16x4*)(xs + idx) = o;
}

__global__ __launch_bounds__(256)
void bias_kernel(const void* __restrict__ qt, const void* __restrict__ st,
                 const void* __restrict__ freq, const void* __restrict__ phase,
                 const void* __restrict__ tw, float* __restrict__ biasAll,
                 const int* __restrict__ flag)
{
    const int f32 = *flag;
    const int lane = threadIdx.x & 63;
    const int bq = blockIdx.x * 4 + (threadIdx.x >> 6);
    const int b = bq >> 5, qq = bq & 31;
    const int i = lane >> 3, jj = lane & 7;
    const float ti = (i  == 0) ? ldf(qt, b * 32 + qq, f32) : ldf(st, b * 7 + i  - 1, f32);
    const float tj = (jj == 0) ? ldf(qt, b * 32 + qq, f32) : ldf(st, b * 7 + jj - 1, f32);
    const float td = ti - tj;
    float a[6] = {0.f, 0.f, 0.f, 0.f, 0.f, 0.f};
    for (int t = 0; t < 32; ++t) {
        float c = __cosf(td * ldf(freq, t, f32) + ldf(phase, t, f32));
#pragma unroll
        for (int l = 0; l < 6; ++l) a[l] += c * ldf(tw, l * 32 + t, f32);
    }
#pragma unroll
    for (int l = 0; l < 6; ++l)
        biasAll[(size_t)l * (4096 * 64) + (size_t)bq * 64 + lane] = a[l];
}

__global__ __launch_bounds__(256)
void transpose_cvt(const void* __restrict__ W, f16* __restrict__ WT,
                   int K, int N, long zsW, long zsWT, const int* __restrict__ flag)
{
    const int f32 = *flag;
    const size_t zoff = (size_t)blockIdx.z * zsW;
    f16* WTz = WT + (size_t)blockIdx.z * zsWT;
    __shared__ float tile[64][65];
    const int tn = blockIdx.x * 64, tk = blockIdx.y * 64;
#pragma unroll
    for (int t = 0; t < 16; ++t) {
        int idx = t * 256 + threadIdx.x;
        int r = idx >> 6, c = idx & 63;
        tile[r][c] = ldf(W, zoff + (size_t)(tk + r) * N + tn + c, f32);
    }
    __syncthreads();
#pragma unroll
    for (int t = 0; t < 16; ++t) {
        int idx = t * 256 + threadIdx.x;
        int r = idx >> 6, c = idx & 63;
        WTz[(size_t)(tn + r) * K + tk + c] = (f16)tile[c][r];
    }
}

__global__ __launch_bounds__(256)
void gather_qkvb(const void* __restrict__ bq, const void* __restrict__ bk,
                 const void* __restrict__ bv, float* __restrict__ dst,
                 const int* __restrict__ flag)
{
    const int f32 = *flag;
    int i = blockIdx.x * 256 + threadIdx.x;
    if (i < 9216) {
        int z = i / 3072, rem = i % 3072;
        const void* src = (z == 0) ? bq : ((z == 1) ? bk : bv);
        dst[i] = ldf(src, rem, f32);
    }
}

__global__ __launch_bounds__(256)
void bn_reduce(const float* __restrict__ h0, float* __restrict__ stats)
{
    const int t = blockIdx.x * 256 + threadIdx.x;
    float s = 0.f, ss = 0.f;
#pragma unroll
    for (int k = 0; k < 8; ++k) {
        float v = h0[t + k * 65536];
        s += v; ss += v * v;
    }
#pragma unroll
    for (int m = 1; m <= 32; m <<= 1) {
        s  += __shfl_xor(s, m, 64);
        ss += __shfl_xor(ss, m, 64);
    }
    __shared__ float ls[8];
    const int w = threadIdx.x >> 6, lane = threadIdx.x & 63;
    if (lane == 0) { ls[w] = s; ls[4 + w] = ss; }
    __syncthreads();
    if (threadIdx.x == 0) {
        atomicAdd(&stats[0], ls[0] + ls[1] + ls[2] + ls[3]);
        atomicAdd(&stats[1], ls[4] + ls[5] + ls[6] + ls[7]);
    }
}

__global__ __launch_bounds__(256)
void bn_apply(const float* __restrict__ h0, const float* __restrict__ stats,
              const float* __restrict__ bnp, float* __restrict__ out)
{
    const int t = blockIdx.x * 256 + threadIdx.x;
    const float mu  = stats[0] * (1.0f / 524288.0f);
    const float var = stats[1] * (1.0f / 524288.0f) - mu * mu;
    const float rs  = rsqrtf(var + 1e-5f);
    float v = bnp[0] * (h0[t] - mu) * rs + bnp[8];
    v = (v >= 0.f) ? v : 0.01f * v;
    out[t] = v;
}

// =====================================================================
extern "C" void kernel_launch(void* const* d_in, const int* in_sizes, int n_in,
                              void* d_out, int out_size, void* d_ws, size_t ws_size,
                              hipStream_t stream)
{
    (void)in_sizes; (void)n_in; (void)out_size;
    const void* sup   = d_in[0];
    const void* qt    = d_in[1];
    const void* st    = d_in[2];
    const void* cls   = d_in[3];
    const void* freq  = d_in[4];
    const void* phase = d_in[5];
    const void* Wq = d_in[6];  const void* bqv = d_in[7];
    const void* Wk = d_in[8];  const void* bkv = d_in[9];
    const void* Wv = d_in[10]; const void* bvv = d_in[11];
    const void* Wo = d_in[12]; const void* bo  = d_in[13];
    const void* ln1g = d_in[14]; const void* ln1b = d_in[15];
    const void* tw = d_in[16];
    const void* W1 = d_in[17]; const void* b1 = d_in[18];
    const void* W2 = d_in[19]; const void* b2 = d_in[20];
    const void* ln2g = d_in[21]; const void* ln2b = d_in[22];
    const void* Wc = d_in[23]; const void* bc = d_in[24];
    const void* bng = d_in[25]; const void* bnb = d_in[26];

    const size_t NEEDED = 245658240;
    if (ws_size < NEEDED) {
        fill_out<<<2048, 256, 0, stream>>>((float*)d_out, 999.0f);
        return;
    }

    char* ws = (char*)d_ws;
    f16*   wt      = (f16*)(ws + 0);              // 37,879,808 B
    float* biasAll = (float*)(ws + 37879808);     // 6,291,456 B
    float* qkvb    = (float*)(ws + 44171264);
    float* prm     = (float*)(ws + 44208128);
    float* stats   = (float*)(ws + 44331584);
    int*   flag    = (int*)  (ws + 44331592);
    f16*   xb      = (f16*)(ws + 44331648);       // 33,554,432 B (x / preLN2)
    f16*   ob      = (f16*)(ws + 77886080);       // 33,554,432 B (LN1 out)
    char*  region  = ws + 111440512;              // 134,217,728 B pool
    f16*   qb      = (f16*)(region);
    f16*   kb      = (f16*)(region + 33554432);
    f16*   vb      = (f16*)(region + 67108864);
    f16*   cb      = (f16*)(region + 100663296);
    f16*   qs      = (f16*)(region);              // layer-0 small QKV (3 MB)
    f16*   xs      = (f16*)(region + 100663296);  // deduped x0 (dead before cb)
    f16*   pl1     = (f16*)(region);              // preLN1 f16 (32 MB, over q slot)
    f16*   fbuf    = (f16*)(region);              // FFN mid full-M (134 MB exact)
    float* h0      = (float*)(region);            // 4096*128 f32

    detect_dtype<<<1, 64, 0, stream>>>(qt, flag);

    // staged fp32 params: bo@0, b1@3072, b2@15360, bc@18432, ln1g@18560,
    // ln1b@21632, ln2g@24704, ln2b@27776, bng@30848, bnb@30856
    cvt_in<<<12, 256, 0, stream>>>(bo,   prm + 0,     3072,  flag);
    cvt_in<<<48, 256, 0, stream>>>(b1,   prm + 3072,  12288, flag);
    cvt_in<<<12, 256, 0, stream>>>(b2,   prm + 15360, 3072,  flag);
    cvt_in<<<1,  256, 0, stream>>>(bc,   prm + 18432, 128,   flag);
    cvt_in<<<12, 256, 0, stream>>>(ln1g, prm + 18560, 3072,  flag);
    cvt_in<<<12, 256, 0, stream>>>(ln1b, prm + 21632, 3072,  flag);
    cvt_in<<<12, 256, 0, stream>>>(ln2g, prm + 24704, 3072,  flag);
    cvt_in<<<12, 256, 0, stream>>>(ln2b, prm + 27776, 3072,  flag);
    cvt_in<<<1,  256, 0, stream>>>(bng,  prm + 30848, 8,     flag);
    cvt_in<<<1,  256, 0, stream>>>(bnb,  prm + 30856, 8,     flag);

    transpose_cvt<<<dim3(8, 8, 6),  256, 0, stream>>>(Wq, wt + 0,        512, 512,  262144, 262144, flag);
    transpose_cvt<<<dim3(8, 8, 6),  256, 0, stream>>>(Wk, wt + 1572864,  512, 512,  262144, 262144, flag);
    transpose_cvt<<<dim3(8, 8, 6),  256, 0, stream>>>(Wv, wt + 3145728,  512, 512,  262144, 262144, flag);
    transpose_cvt<<<dim3(8, 8, 6),  256, 0, stream>>>(Wo, wt + 4718592,  512, 512,  262144, 262144, flag);
    transpose_cvt<<<dim3(32, 8, 6), 256, 0, stream>>>(W1, wt + 6291456,  512, 2048, 1048576, 1048576, flag);
    transpose_cvt<<<dim3(8, 32, 6), 256, 0, stream>>>(W2, wt + 12582912, 2048, 512, 1048576, 1048576, flag);
    transpose_cvt<<<dim3(2, 8, 1),  256, 0, stream>>>(Wc, wt + 18874368, 512, 128,  0, 0, flag);
    gather_qkvb<<<36, 256, 0, stream>>>(bqv, bkv, bvv, qkvb, flag);
    build_x0<<<16384, 256, 0, stream>>>(sup, cls, xb, flag);
    build_x0s<<<512, 256, 0, stream>>>(sup, cls, xs, flag);
    bias_kernel<<<1024, 256, 0, stream>>>(qt, st, freq, phase, tw, biasAll, flag);
    hipMemsetAsync(stats, 0, 8, stream);

    for (int l = 0; l < 6; ++l) {
        if (l == 0) {
            // deduped QKV on 1024 distinct rows -> qs (3 slabs of 1 MB)
            gemm_bt<0><<<96, 256, 0, stream>>>(
                xs, wt, qkvb, nullptr, qs,
                4, 12, 8, 1, 512, 512, 512, 1572864, 3072, 524288);
            attn_kernel<<<4096, 256, 0, stream>>>(
                qs, qs + 524288, qs + 1048576, biasAll, cb, 1);
        } else {
            gemm_bt<0><<<1536, 256, 0, stream>>>(
                xb, wt + l * 262144, qkvb + l * 512, nullptr, qb,
                4, 12, 32, 2, 512, 512, 512, 1572864, 3072, 16777216);
            attn_kernel<<<4096, 256, 0, stream>>>(
                qb, kb, vb, biasAll + (size_t)l * 262144, cb, 0);
        }
        // O-proj + bias + residual(xb) -> pl1
        gemm_bt<1><<<1024, 256, 0, stream>>>(
            cb, wt + 4718592 + l * 262144, prm + 0 + l * 512, xb, pl1,
            4, 4, 64, 1, 512, 512, 512, 0, 0, 0);
        ln_kernel<<<8192, 256, 0, stream>>>(pl1, prm + 18560 + l * 512, prm + 21632 + l * 512, ob);
        // FFN full-M: fbuf takes whole region; preLN2 goes into xb (free now)
        gemm_bt<2><<<2048, 256, 0, stream>>>(
            ob, wt + 6291456 + l * 1048576, prm + 3072 + l * 2048, nullptr, fbuf,
            16, 16, 32, 2, 2048, 512, 512, 0, 0, 0);
        gemm_bt<1><<<1024, 256, 0, stream>>>(
            fbuf, wt + 12582912 + l * 1048576, prm + 15360 + l * 512, ob, xb,
            4, 4, 64, 1, 512, 2048, 2048, 0, 0, 0);
        ln_kernel<<<8192, 256, 0, stream>>>(xb, prm + 24704 + l * 512, prm + 27776 + l * 512, xb);
    }

    gemm_bt<3><<<32, 256, 0, stream>>>(
        xb, wt + 18874368, prm + 18432, nullptr, h0,
        1, 1, 32, 1, 128, 512, 4096 /* s==0 rows: stride 8*512 */, 0, 0, 0);
    bn_reduce<<<256, 256, 0, stream>>>(h0, stats);
    bn_apply<<<2048, 256, 0, stream>>>(h0, stats, prm + 30848, (float*)d_out);
}

// Round 8
// 2789.864 us; speedup vs baseline: 1.1643x; 1.1643x over previous
//
#include <hip/hip_runtime.h>
#include <hip/hip_bf16.h>

typedef _Float16 f16;
typedef __attribute__((ext_vector_type(8))) _Float16 f16x8;
typedef __attribute__((ext_vector_type(4))) _Float16 f16x4;
typedef __attribute__((ext_vector_type(4))) float f32x4;

#define DEVI __device__ __forceinline__

DEVI float ldf(const void* p, size_t i, int isf32) {
    if (isf32) return ((const float*)p)[i];
    unsigned int u = ((const unsigned short*)p)[i];
    union { unsigned int b; float f; } c; c.b = u << 16;
    return c.f;
}

DEVI void gld_lds16(const f16* g, f16* l) {
    __builtin_amdgcn_global_load_lds(
        (__attribute__((address_space(1))) void*)(g),
        (__attribute__((address_space(3))) void*)(l), 16, 0, 0);
}

__global__ void detect_dtype(const void* qt, int* flag) {
    if (threadIdx.x == 0 && blockIdx.x == 0) {
        const unsigned int* w = (const unsigned int*)qt;
        int cnt = 0;
        for (int i = 0; i < 64; ++i) {
            unsigned int lo = w[i] & 0xFFFFu;
            union { unsigned int b; float f; } c; c.b = lo << 16;
            if (c.f >= 1e-4f && c.f <= 100.5f) ++cnt;
        }
        *flag = (cnt >= 32) ? 0 : 1;   // 0 = bf16, 1 = fp32
    }
}

__global__ __launch_bounds__(256)
void cvt_in(const void* __restrict__ src, float* __restrict__ dst, int n,
            const int* __restrict__ flag) {
    const int f32 = *flag;
    int i = blockIdx.x * 256 + threadIdx.x;
    if (i < n) dst[i] = ldf(src, i, f32);
}

__global__ __launch_bounds__(256)
void fill_out(float* out, float v) {
    out[blockIdx.x * 256 + threadIdx.x] = v;
}

// =====================================================================
// gemm_bt: 4-wave 128x128 MFMA GEMM (QKV / FFN1 / compress), BK=32 dbuf
// pipelined, swizzled 1D grid. EPI: 0 bias->f16 ; 2 bias+gelu->f16 ;
// 3 bias->f32
// =====================================================================
template<int EPI>
__global__ __launch_bounds__(256, 4)
void gemm_bt(const f16* __restrict__ Ag, const f16* __restrict__ BTg,
             const float* __restrict__ biasg, const f16* __restrict__ resg,
             void* __restrict__ outg,
             int NT, int NTZ, int MCHUNK, int MT, int N, int K, int lda,
             long zsB, long zsBias, long zsC)
{
    const int tid  = threadIdx.x;
    const int w    = tid >> 6, lane = tid & 63;
    const int wm   = w >> 1,   wn   = w & 1;

    const int id    = blockIdx.x;
    const int pc    = MCHUNK * NTZ;
    const int chunk = id / pc;
    const int rem   = id - chunk * pc;
    const int mloc  = rem % MCHUNK;
    const int ynz   = rem / MCHUNK;
    const int z     = ynz / NT;
    const int tmB   = (chunk * MCHUNK + mloc) * (128 * MT);
    const int tn    = (ynz - z * NT) * 128;

    const f16*   BT   = BTg + (size_t)z * zsB;
    const float* bias = biasg + (size_t)z * zsBias;
    const size_t zoffC = (size_t)z * zsC;

    __shared__ __align__(16) f16 smA[2][8][64][8];
    __shared__ __align__(16) f16 smB[2][8][64][8];

    const int r16 = lane & 15, q4 = lane >> 4;
    const int iters = K >> 5;

    const f16* gA0 = Ag + (size_t)(tmB + (2 * w) * 16 + r16) * lda + q4 * 8;
    const f16* gA1 = gA0 + (size_t)16 * lda;
    const f16* gB0 = BT + (size_t)(tn + (2 * w) * 16 + r16) * K + q4 * 8;
    const f16* gB1 = gB0 + (size_t)16 * K;

    auto issue = [&](int msN, int ktN, int buf) {
        const size_t aoff = (size_t)msN * 128 * lda + (size_t)ktN * 32;
        const size_t boff = (size_t)ktN * 32;
        gld_lds16(gA0 + aoff, &smA[buf][2 * w][0][0]);
        gld_lds16(gA1 + aoff, &smA[buf][2 * w + 1][0][0]);
        gld_lds16(gB0 + boff, &smB[buf][2 * w][0][0]);
        gld_lds16(gB1 + boff, &smB[buf][2 * w + 1][0][0]);
    };

    issue(0, 0, 0);
    int stage = 0;

    for (int ms = 0; ms < MT; ++ms) {
        const int tm = tmB + ms * 128;

        f32x4 acc[4][4];
#pragma unroll
        for (int i = 0; i < 4; ++i)
#pragma unroll
            for (int j = 0; j < 4; ++j) acc[i][j] = (f32x4)0.0f;

        for (int kt = 0; kt < iters; ++kt, ++stage) {
            const int cur = stage & 1;
            __builtin_amdgcn_s_barrier();
            int ktN = kt + 1, msN = ms;
            if (ktN == iters) { ktN = 0; ++msN; }
            if (msN < MT) {
                issue(msN, ktN, cur ^ 1);
                __builtin_amdgcn_s_waitcnt(0x0F74);  // vmcnt(4)
            } else {
                __builtin_amdgcn_s_waitcnt(0x0F70);  // vmcnt(0)
            }
            __builtin_amdgcn_s_barrier();
            __asm__ __volatile__("" ::: "memory");

            f16x8 af[4], bf[4];
#pragma unroll
            for (int i = 0; i < 4; ++i) {
                af[i] = *(const f16x8*)&smA[cur][wm * 4 + i][lane][0];
                bf[i] = *(const f16x8*)&smB[cur][wn * 4 + i][lane][0];
            }
#pragma unroll
            for (int i = 0; i < 4; ++i)
#pragma unroll
                for (int j = 0; j < 4; ++j)
                    acc[i][j] = __builtin_amdgcn_mfma_f32_16x16x32_f16(
                        af[i], bf[j], acc[i][j], 0, 0, 0);
        }

        const int rowBase = tm + wm * 64;
        const int colBase = tn + wn * 64;
#pragma unroll
        for (int j = 0; j < 4; ++j) {
            const int col = colBase + j * 16 + r16;
            const float bv = bias[col];
#pragma unroll
            for (int i = 0; i < 4; ++i) {
                const int row0 = rowBase + i * 16 + q4 * 4;
#pragma unroll
                for (int r = 0; r < 4; ++r) {
                    const int row = row0 + r;
                    const size_t off = (size_t)row * N + col;
                    float v = acc[i][j][r] + bv;
                    if constexpr (EPI == 0) {
                        ((f16*)outg)[zoffC + off] = (f16)v;
                    } else if constexpr (EPI == 2) {
                        float t  = v + 0.044715f * v * v * v;
                        float u  = 1.5957691216057308f * t;   // 2*sqrt(2/pi)*t
                        float e  = __expf(u);
                        float th = 1.0f - 2.0f / (e + 1.0f); // tanh(u/2)
                        ((f16*)outg)[off] = (f16)(0.5f * v * (1.0f + th));
                    } else {
                        ((float*)outg)[off] = v;
                    }
                }
            }
        }
    }
}

// =====================================================================
// gemm_ln: 8-wave 128x512 fused GEMM + bias + residual + LayerNorm.
// C = A[128,K] @ BT[512,K]^T + bias + res ; Y = LN(C) * g + b -> f16.
// Wave (wm=w>>2, wn=w&3) computes 64x128. BK=32 dbuf pipeline (raw
// barriers + vmcnt(5)). Grid = M/128 blocks, 1 block/CU; B broadcast
// through L2 (all blocks read the same B-tile each stage).
// =====================================================================
__global__ __launch_bounds__(512, 2)
void gemm_ln(const f16* __restrict__ Ag, const f16* __restrict__ BTg,
             const float* __restrict__ bias, const f16* __restrict__ resg,
             const float* __restrict__ lng, const float* __restrict__ lnb,
             f16* __restrict__ Yg, int K, int lda)
{
    const int tid = threadIdx.x;
    const int w = tid >> 6, lane = tid & 63;
    const int wm = w >> 2, wn = w & 3;
    const int r16 = lane & 15, q4 = lane >> 4;
    const int tm = blockIdx.x * 128;

    __shared__ __align__(16) f16 smA[2][8][64][8];    // 16 KB
    __shared__ __align__(16) f16 smB[2][32][64][8];   // 64 KB
    __shared__ float lnS[128][4];
    __shared__ float lnQ[128][4];

    f32x4 acc[4][8];
#pragma unroll
    for (int i = 0; i < 4; ++i)
#pragma unroll
        for (int j = 0; j < 8; ++j) acc[i][j] = (f32x4)0.0f;

    // staging: wave w owns A sub-block w (rows w*16+r16) and B sub-blocks
    // w*4..w*4+3 (rows w*64 + t*16 + r16)
    const f16* gA  = Ag  + (size_t)(tm + w * 16 + r16) * lda + q4 * 8;
    const f16* gB  = BTg + (size_t)(w * 64 + r16) * K + q4 * 8;
    const int iters = K >> 5;

    auto issue = [&](int kt, int buf) {
        const size_t o = (size_t)kt * 32;
        gld_lds16(gA + o, &smA[buf][w][0][0]);
#pragma unroll
        for (int t = 0; t < 4; ++t)
            gld_lds16(gB + (size_t)(t * 16) * K + o, &smB[buf][w * 4 + t][0][0]);
    };

    issue(0, 0);
    for (int kt = 0; kt < iters; ++kt) {
        const int cur = kt & 1;
        __builtin_amdgcn_s_barrier();
        if (kt + 1 < iters) {
            issue(kt + 1, cur ^ 1);
            __builtin_amdgcn_s_waitcnt(0x0F75);  // vmcnt(5): current 5 done
        } else {
            __builtin_amdgcn_s_waitcnt(0x0F70);  // vmcnt(0)
        }
        __builtin_amdgcn_s_barrier();
        __asm__ __volatile__("" ::: "memory");

        f16x8 af[4], bf[8];
#pragma unroll
        for (int i = 0; i < 4; ++i)
            af[i] = *(const f16x8*)&smA[cur][wm * 4 + i][lane][0];
#pragma unroll
        for (int j = 0; j < 8; ++j)
            bf[j] = *(const f16x8*)&smB[cur][wn * 8 + j][lane][0];
#pragma unroll
        for (int i = 0; i < 4; ++i)
#pragma unroll
            for (int j = 0; j < 8; ++j)
                acc[i][j] = __builtin_amdgcn_mfma_f32_16x16x32_f16(
                    af[i], bf[j], acc[i][j], 0, 0, 0);
    }

    // ---- epilogue: bias + residual, row stats, LN, store ----
    const int rowB = wm * 64;        // block-local row base of this wave
    const int colB = wn * 128;       // block-local col base
    float gv[8], bv[8], biv[8];
#pragma unroll
    for (int j = 0; j < 8; ++j) {
        const int col = colB + j * 16 + r16;
        gv[j] = lng[col]; bv[j] = lnb[col]; biv[j] = bias[col];
    }

    float ps[4][4], pq[4][4];
#pragma unroll
    for (int i = 0; i < 4; ++i) {
#pragma unroll
        for (int rr = 0; rr < 4; ++rr) {
            const int grow = tm + rowB + i * 16 + q4 * 4 + rr;
            float s = 0.f, sq = 0.f;
#pragma unroll
            for (int j = 0; j < 8; ++j) {
                const int col = colB + j * 16 + r16;
                float v = acc[i][j][rr] + biv[j]
                        + (float)resg[(size_t)grow * 512 + col];
                acc[i][j][rr] = v;
                s += v; sq += v * v;
            }
            // reduce over the 16 r16-lanes (same q4) -> wave's 128 cols
#pragma unroll
            for (int m = 1; m <= 8; m <<= 1) {
                s  += __shfl_xor(s, m, 64);
                sq += __shfl_xor(sq, m, 64);
            }
            ps[i][rr] = s; pq[i][rr] = sq;
        }
    }
    __syncthreads();                 // all waves done with smA/smB reads
    if (r16 == 0) {
#pragma unroll
        for (int i = 0; i < 4; ++i)
#pragma unroll
            for (int rr = 0; rr < 4; ++rr) {
                const int lr = rowB + i * 16 + q4 * 4 + rr;
                lnS[lr][wn] = ps[i][rr];
                lnQ[lr][wn] = pq[i][rr];
            }
    }
    __syncthreads();

#pragma unroll
    for (int i = 0; i < 4; ++i) {
#pragma unroll
        for (int rr = 0; rr < 4; ++rr) {
            const int lr = rowB + i * 16 + q4 * 4 + rr;
            const float s  = lnS[lr][0] + lnS[lr][1] + lnS[lr][2] + lnS[lr][3];
            const float sq = lnQ[lr][0] + lnQ[lr][1] + lnQ[lr][2] + lnQ[lr][3];
            const float mu = s * (1.0f / 512.0f);
            const float var = sq * (1.0f / 512.0f) - mu * mu;
            const float rs = rsqrtf(var + 1e-5f);
            const size_t rowoff = (size_t)(tm + lr) * 512;
#pragma unroll
            for (int j = 0; j < 8; ++j) {
                const int col = colB + j * 16 + r16;
                Yg[rowoff + col] = (f16)(gv[j] * (acc[i][j][rr] - mu) * rs + bv[j]);
            }
        }
    }
}

// =====================================================================
// Attention: 1 wave per batch j in [0,16384); slab j*1024 viewed [8][128]
// (raw torch-.view semantics); bias row = j mod 4096.
// small=1: Q/K/V are deduped [1024][512] (layer 0), slab = b*4096 + h*1024.
// =====================================================================
__global__ __launch_bounds__(256)
void attn_kernel(const f16* __restrict__ qg, const f16* __restrict__ kg,
                 const f16* __restrict__ vg, const float* __restrict__ biasL,
                 f16* __restrict__ cg, int small)
{
    const int w = threadIdx.x >> 6, lane = threadIdx.x & 63;
    const int j = blockIdx.x * 4 + w;
    __shared__ __align__(16) f16 sQ[4][8][136];
    __shared__ __align__(16) f16 sK[4][8][136];
    __shared__ __align__(16) f16 sV[4][8][136];
    __shared__ float sP[4][8][8];

    const size_t base  = (size_t)j * 1024;
    const size_t ibase = small ? ((size_t)(j >> 7) * 4096 + (size_t)(j & 3) * 1024)
                               : base;
#pragma unroll
    for (int t = 0; t < 2; ++t) {
        int flat = (t * 64 + lane) * 8;
        int r = flat >> 7, c = flat & 127;
        *(f16x8*)&sQ[w][r][c] = *(const f16x8*)(qg + ibase + flat);
        *(f16x8*)&sK[w][r][c] = *(const f16x8*)(kg + ibase + flat);
        *(f16x8*)&sV[w][r][c] = *(const f16x8*)(vg + ibase + flat);
    }
    __syncthreads();

    const int i = lane >> 3, jj = lane & 7;
    float d = 0.f;
#pragma unroll
    for (int c = 0; c < 16; ++c) {
        f16x8 qv = *(const f16x8*)&sQ[w][i][c * 8];
        f16x8 kv = *(const f16x8*)&sK[w][jj][c * 8];
#pragma unroll
        for (int e = 0; e < 8; ++e) d += (float)qv[e] * (float)kv[e];
    }
    float s = d * 0.17677669529663687f + biasL[(size_t)(j & 4095) * 64 + lane];
    float mx = s;
    mx = fmaxf(mx, __shfl_xor(mx, 1, 64));
    mx = fmaxf(mx, __shfl_xor(mx, 2, 64));
    mx = fmaxf(mx, __shfl_xor(mx, 4, 64));
    float p = __expf(s - mx);
    float sum = p;
    sum += __shfl_xor(sum, 1, 64);
    sum += __shfl_xor(sum, 2, 64);
    sum += __shfl_xor(sum, 4, 64);
    sP[w][i][jj] = p / sum;
    __syncthreads();

#pragma unroll
    for (int t2 = 0; t2 < 8; ++t2) {
        float ap[8];
#pragma unroll
        for (int e = 0; e < 8; ++e) ap[e] = sP[w][t2][e];
#pragma unroll
        for (int h = 0; h < 2; ++h) {
            int flat = (t2 * 2 + h) * 64 + lane;
            int dd = flat & 127;
            float o = 0.f;
#pragma unroll
            for (int e = 0; e < 8; ++e) o += ap[e] * (float)sV[w][e][dd];
            cg[base + flat] = (f16)o;
        }
    }
}

// =====================================================================
// x0 builders
// =====================================================================
__global__ __launch_bounds__(256)
void build_x0(const void* __restrict__ sup, const void* __restrict__ cls,
              f16* __restrict__ xb, const int* __restrict__ flag)
{
    const int f32 = *flag;
    const size_t idx = ((size_t)blockIdx.x * 256 + threadIdx.x) * 4;
    const int row = (int)(idx >> 9), col0 = (int)(idx & 511);
    const int s = row & 7, b = row >> 8;
    f16x4 o;
#pragma unroll
    for (int e = 0; e < 4; ++e) {
        const int md = (col0 + e) & 127;
        float v = (s == 0) ? ldf(cls, md, f32)
                           : ldf(sup, ((size_t)b * 7 + (s - 1)) * 128 + md, f32);
        o[e] = (f16)v;
    }
    *(f16x4*)(xb + idx) = o;
}

__global__ __launch_bounds__(256)
void build_x0s(const void* __restrict__ sup, const void* __restrict__ cls,
               f16* __restrict__ xs, const int* __restrict__ flag)
{
    const int f32 = *flag;
    const size_t idx = ((size_t)blockIdx.x * 256 + threadIdx.x) * 4;
    const int row = (int)(idx >> 9), col0 = (int)(idx & 511);
    const int s = row & 7, b = row >> 3;
    f16x4 o;
#pragma unroll
    for (int e = 0; e < 4; ++e) {
        const int md = (col0 + e) & 127;
        float v = (s == 0) ? ldf(cls, md, f32)
                           : ldf(sup, ((size_t)b * 7 + (s - 1)) * 128 + md, f32);
        o[e] = (f16)v;
    }
    *(f16x4*)(xs + idx) = o;
}

__global__ __launch_bounds__(256)
void bias_kernel(const void* __restrict__ qt, const void* __restrict__ st,
                 const void* __restrict__ freq, const void* __restrict__ phase,
                 const void* __restrict__ tw, float* __restrict__ biasAll,
                 const int* __restrict__ flag)
{
    const int f32 = *flag;
    const int lane = threadIdx.x & 63;
    const int bq = blockIdx.x * 4 + (threadIdx.x >> 6);
    const int b = bq >> 5, qq = bq & 31;
    const int i = lane >> 3, jj = lane & 7;
    const float ti = (i  == 0) ? ldf(qt, b * 32 + qq, f32) : ldf(st, b * 7 + i  - 1, f32);
    const float tj = (jj == 0) ? ldf(qt, b * 32 + qq, f32) : ldf(st, b * 7 + jj - 1, f32);
    const float td = ti - tj;
    float a[6] = {0.f, 0.f, 0.f, 0.f, 0.f, 0.f};
    for (int t = 0; t < 32; ++t) {
        float c = __cosf(td * ldf(freq, t, f32) + ldf(phase, t, f32));
#pragma unroll
        for (int l = 0; l < 6; ++l) a[l] += c * ldf(tw, l * 32 + t, f32);
    }
#pragma unroll
    for (int l = 0; l < 6; ++l)
        biasAll[(size_t)l * (4096 * 64) + (size_t)bq * 64 + lane] = a[l];
}

__global__ __launch_bounds__(256)
void transpose_cvt(const void* __restrict__ W, f16* __restrict__ WT,
                   int K, int N, long zsW, long zsWT, const int* __restrict__ flag)
{
    const int f32 = *flag;
    const size_t zoff = (size_t)blockIdx.z * zsW;
    f16* WTz = WT + (size_t)blockIdx.z * zsWT;
    __shared__ float tile[64][65];
    const int tn = blockIdx.x * 64, tk = blockIdx.y * 64;
#pragma unroll
    for (int t = 0; t < 16; ++t) {
        int idx = t * 256 + threadIdx.x;
        int r = idx >> 6, c = idx & 63;
        tile[r][c] = ldf(W, zoff + (size_t)(tk + r) * N + tn + c, f32);
    }
    __syncthreads();
#pragma unroll
    for (int t = 0; t < 16; ++t) {
        int idx = t * 256 + threadIdx.x;
        int r = idx >> 6, c = idx & 63;
        WTz[(size_t)(tn + r) * K + tk + c] = (f16)tile[c][r];
    }
}

__global__ __launch_bounds__(256)
void gather_qkvb(const void* __restrict__ bq, const void* __restrict__ bk,
                 const void* __restrict__ bv, float* __restrict__ dst,
                 const int* __restrict__ flag)
{
    const int f32 = *flag;
    int i = blockIdx.x * 256 + threadIdx.x;
    if (i < 9216) {
        int z = i / 3072, rem = i % 3072;
        const void* src = (z == 0) ? bq : ((z == 1) ? bk : bv);
        dst[i] = ldf(src, rem, f32);
    }
}

__global__ __launch_bounds__(256)
void bn_reduce(const float* __restrict__ h0, float* __restrict__ stats)
{
    const int t = blockIdx.x * 256 + threadIdx.x;
    float s = 0.f, ss = 0.f;
#pragma unroll
    for (int k = 0; k < 8; ++k) {
        float v = h0[t + k * 65536];
        s += v; ss += v * v;
    }
#pragma unroll
    for (int m = 1; m <= 32; m <<= 1) {
        s  += __shfl_xor(s, m, 64);
        ss += __shfl_xor(ss, m, 64);
    }
    __shared__ float ls[8];
    const int w = threadIdx.x >> 6, lane = threadIdx.x & 63;
    if (lane == 0) { ls[w] = s; ls[4 + w] = ss; }
    __syncthreads();
    if (threadIdx.x == 0) {
        atomicAdd(&stats[0], ls[0] + ls[1] + ls[2] + ls[3]);
        atomicAdd(&stats[1], ls[4] + ls[5] + ls[6] + ls[7]);
    }
}

__global__ __launch_bounds__(256)
void bn_apply(const float* __restrict__ h0, const float* __restrict__ stats,
              const float* __restrict__ bnp, float* __restrict__ out)
{
    const int t = blockIdx.x * 256 + threadIdx.x;
    const float mu  = stats[0] * (1.0f / 524288.0f);
    const float var = stats[1] * (1.0f / 524288.0f) - mu * mu;
    const float rs  = rsqrtf(var + 1e-5f);
    float v = bnp[0] * (h0[t] - mu) * rs + bnp[8];
    v = (v >= 0.f) ? v : 0.01f * v;
    out[t] = v;
}

// =====================================================================
extern "C" void kernel_launch(void* const* d_in, const int* in_sizes, int n_in,
                              void* d_out, int out_size, void* d_ws, size_t ws_size,
                              hipStream_t stream)
{
    (void)in_sizes; (void)n_in; (void)out_size;
    const void* sup   = d_in[0];
    const void* qt    = d_in[1];
    const void* st    = d_in[2];
    const void* cls   = d_in[3];
    const void* freq  = d_in[4];
    const void* phase = d_in[5];
    const void* Wq = d_in[6];  const void* bqv = d_in[7];
    const void* Wk = d_in[8];  const void* bkv = d_in[9];
    const void* Wv = d_in[10]; const void* bvv = d_in[11];
    const void* Wo = d_in[12]; const void* bo  = d_in[13];
    const void* ln1g = d_in[14]; const void* ln1b = d_in[15];
    const void* tw = d_in[16];
    const void* W1 = d_in[17]; const void* b1 = d_in[18];
    const void* W2 = d_in[19]; const void* b2 = d_in[20];
    const void* ln2g = d_in[21]; const void* ln2b = d_in[22];
    const void* Wc = d_in[23]; const void* bc = d_in[24];
    const void* bng = d_in[25]; const void* bnb = d_in[26];

    const size_t NEEDED = 245658240;
    if (ws_size < NEEDED) {
        fill_out<<<2048, 256, 0, stream>>>((float*)d_out, 999.0f);
        return;
    }

    char* ws = (char*)d_ws;
    f16*   wt      = (f16*)(ws + 0);              // 37,879,808 B
    float* biasAll = (float*)(ws + 37879808);     // 6,291,456 B
    float* qkvb    = (float*)(ws + 44171264);
    float* prm     = (float*)(ws + 44208128);
    float* stats   = (float*)(ws + 44331584);
    int*   flag    = (int*)  (ws + 44331592);
    f16*   xb      = (f16*)(ws + 44331648);       // 33,554,432 B
    f16*   ob      = (f16*)(ws + 77886080);       // 33,554,432 B
    char*  region  = ws + 111440512;              // 134,217,728 B pool
    f16*   qb      = (f16*)(region);
    f16*   kb      = (f16*)(region + 33554432);
    f16*   vb      = (f16*)(region + 67108864);
    f16*   cb      = (f16*)(region + 100663296);
    f16*   qs      = (f16*)(region);              // layer-0 small QKV
    f16*   xs      = (f16*)(region + 100663296);  // deduped x0
    f16*   fbuf    = (f16*)(region);              // FFN mid full-M (134 MB)
    float* h0      = (float*)(region);            // 4096*128 f32

    detect_dtype<<<1, 64, 0, stream>>>(qt, flag);

    cvt_in<<<12, 256, 0, stream>>>(bo,   prm + 0,     3072,  flag);
    cvt_in<<<48, 256, 0, stream>>>(b1,   prm + 3072,  12288, flag);
    cvt_in<<<12, 256, 0, stream>>>(b2,   prm + 15360, 3072,  flag);
    cvt_in<<<1,  256, 0, stream>>>(bc,   prm + 18432, 128,   flag);
    cvt_in<<<12, 256, 0, stream>>>(ln1g, prm + 18560, 3072,  flag);
    cvt_in<<<12, 256, 0, stream>>>(ln1b, prm + 21632, 3072,  flag);
    cvt_in<<<12, 256, 0, stream>>>(ln2g, prm + 24704, 3072,  flag);
    cvt_in<<<12, 256, 0, stream>>>(ln2b, prm + 27776, 3072,  flag);
    cvt_in<<<1,  256, 0, stream>>>(bng,  prm + 30848, 8,     flag);
    cvt_in<<<1,  256, 0, stream>>>(bnb,  prm + 30856, 8,     flag);

    transpose_cvt<<<dim3(8, 8, 6),  256, 0, stream>>>(Wq, wt + 0,        512, 512,  262144, 262144, flag);
    transpose_cvt<<<dim3(8, 8, 6),  256, 0, stream>>>(Wk, wt + 1572864,  512, 512,  262144, 262144, flag);
    transpose_cvt<<<dim3(8, 8, 6),  256, 0, stream>>>(Wv, wt + 3145728,  512, 512,  262144, 262144, flag);
    transpose_cvt<<<dim3(8, 8, 6),  256, 0, stream>>>(Wo, wt + 4718592,  512, 512,  262144, 262144, flag);
    transpose_cvt<<<dim3(32, 8, 6), 256, 0, stream>>>(W1, wt + 6291456,  512, 2048, 1048576, 1048576, flag);
    transpose_cvt<<<dim3(8, 32, 6), 256, 0, stream>>>(W2, wt + 12582912, 2048, 512, 1048576, 1048576, flag);
    transpose_cvt<<<dim3(2, 8, 1),  256, 0, stream>>>(Wc, wt + 18874368, 512, 128,  0, 0, flag);
    gather_qkvb<<<36, 256, 0, stream>>>(bqv, bkv, bvv, qkvb, flag);
    build_x0<<<16384, 256, 0, stream>>>(sup, cls, xb, flag);
    build_x0s<<<512, 256, 0, stream>>>(sup, cls, xs, flag);
    bias_kernel<<<1024, 256, 0, stream>>>(qt, st, freq, phase, tw, biasAll, flag);
    hipMemsetAsync(stats, 0, 8, stream);

    for (int l = 0; l < 6; ++l) {
        if (l == 0) {
            gemm_bt<0><<<96, 256, 0, stream>>>(
                xs, wt, qkvb, nullptr, qs,
                4, 12, 8, 1, 512, 512, 512, 1572864, 3072, 524288);
            attn_kernel<<<4096, 256, 0, stream>>>(
                qs, qs + 524288, qs + 1048576, biasAll, cb, 1);
        } else {
            gemm_bt<0><<<1536, 256, 0, stream>>>(
                xb, wt + l * 262144, qkvb + l * 512, nullptr, qb,
                4, 12, 32, 2, 512, 512, 512, 1572864, 3072, 16777216);
            attn_kernel<<<4096, 256, 0, stream>>>(
                qb, kb, vb, biasAll + (size_t)l * 262144, cb, 0);
        }
        // O-proj + bias + residual(xb) + LN1 -> ob  (fused)
        gemm_ln<<<256, 512, 0, stream>>>(
            cb, wt + 4718592 + l * 262144, prm + 0 + l * 512, xb,
            prm + 18560 + l * 512, prm + 21632 + l * 512, ob, 512, 512);
        // FFN1 + gelu -> fbuf
        gemm_bt<2><<<2048, 256, 0, stream>>>(
            ob, wt + 6291456 + l * 1048576, prm + 3072 + l * 2048, nullptr, fbuf,
            16, 16, 32, 2, 2048, 512, 512, 0, 0, 0);
        // FFN2 + bias + residual(ob) + LN2 -> xb  (fused)
        gemm_ln<<<256, 512, 0, stream>>>(
            fbuf, wt + 12582912 + l * 1048576, prm + 15360 + l * 512, ob,
            prm + 24704 + l * 512, prm + 27776 + l * 512, xb, 2048, 2048);
    }

    gemm_bt<3><<<32, 256, 0, stream>>>(
        xb, wt + 18874368, prm + 18432, nullptr, h0,
        1, 1, 32, 1, 128, 512, 4096 /* s==0 rows: stride 8*512 */, 0, 0, 0);
    bn_reduce<<<256, 256, 0, stream>>>(h0, stats);
    bn_apply<<<2048, 256, 0, stream>>>(h0, stats, prm + 30848, (float*)d_out);
}